// Round 11
// baseline (230.132 us; speedup 1.0000x reference)
//
#include <hip/hip_runtime.h>

typedef __attribute__((ext_vector_type(8))) __bf16 bf16x8;
typedef __attribute__((ext_vector_type(4))) __bf16 bf16x4;
typedef __attribute__((ext_vector_type(4))) float f32x4;

#define D_OUT 4096
#define D_IN  4096
#define RANK  512
#define MROWS 8192   // BATCH*SEQ

__device__ __forceinline__ void gload_lds16(const void* gsrc, void* ldst) {
  __builtin_amdgcn_global_load_lds(
      (const __attribute__((address_space(1))) void*)gsrc,
      (__attribute__((address_space(3))) void*)ldst, 16, 0, 0);
}

// ---------------- f32 -> bf16 elementwise convert (A) ----------------
__global__ __launch_bounds__(256) void cvt_f32_bf16(const float* __restrict__ in,
                                                    __bf16* __restrict__ out,
                                                    size_t n) {
  size_t i = ((size_t)blockIdx.x * 256 + threadIdx.x) * 4;
  size_t stride = (size_t)gridDim.x * 256 * 4;
  for (; i < n; i += stride) {
    float4 v = *(const float4*)(in + i);
    bf16x4 o = {(__bf16)v.x, (__bf16)v.y, (__bf16)v.z, (__bf16)v.w};
    *(bf16x4*)(out + i) = o;
  }
}

// ------------- f32 [R][C] -> bf16 [C][R] transpose-convert (B) -------------
__global__ __launch_bounds__(256) void transpose_cvt(const float* __restrict__ in,
                                                     __bf16* __restrict__ out,
                                                     int R, int C) {
  __shared__ __bf16 tile[64][72];
  const int r0 = blockIdx.x * 64, c0 = blockIdx.y * 64;
  const int t = threadIdx.x;
  const int tr = t / 16, tc4 = (t % 16) * 4;
#pragma unroll
  for (int i = 0; i < 4; ++i) {
    int r = i * 16 + tr;
    float4 v = *(const float4*)(in + (size_t)(r0 + r) * C + c0 + tc4);
    tile[r][tc4 + 0] = (__bf16)v.x;
    tile[r][tc4 + 1] = (__bf16)v.y;
    tile[r][tc4 + 2] = (__bf16)v.z;
    tile[r][tc4 + 3] = (__bf16)v.w;
  }
  __syncthreads();
#pragma unroll
  for (int i = 0; i < 4; ++i) {
    int c = i * 16 + tr;
    bf16x4 o = {tile[tc4 + 0][c], tile[tc4 + 1][c], tile[tc4 + 2][c], tile[tc4 + 3][c]};
    *(bf16x4*)(out + (size_t)(c0 + c) * R + r0 + tc4) = o;
  }
}

// ---------------- partial-sum reduce + cvt: o = bf16(t0 + t1) ----------------
__global__ __launch_bounds__(256) void reduce2_bf16(const __bf16* __restrict__ t0,
                                                    const __bf16* __restrict__ t1,
                                                    __bf16* __restrict__ o) {
  size_t i = ((size_t)blockIdx.x * 256 + threadIdx.x) * 8;
  bf16x8 a = *(const bf16x8*)(t0 + i);
  bf16x8 b = *(const bf16x8*)(t1 + i);
  bf16x8 r;
#pragma unroll
  for (int j = 0; j < 8; ++j) r[j] = (__bf16)((float)a[j] + (float)b[j]);
  *(bf16x8*)(o + i) = r;
}

// ==== GEMM1 A-direct: C = bf16(Xf32) @ Bmat^T, bf16 partials per z-slice ====
// A-operand (x, f32) bypasses LDS entirely: each lane loads its MFMA fragment
// (8 consecutive K-elems) via 2x global_load_dwordx4 per (mi,kk) and converts
// f32->bf16 in VALU. LDS holds only the B tile (16 KB). Cuts per-tile LDS
// traffic 144->48 KB and removes all A bank conflicts. Split-K via blockIdx.z.
// R10 bug fixed: B tile needs FOUR 4KB staging issues (was 2 -> half-staged
// tile -> uninitialized-LDS NaNs).
__global__ __launch_bounds__(256) void gemm1_adirect(const float* __restrict__ Xf,
                                                     const __bf16* __restrict__ Bmat,
                                                     __bf16* __restrict__ Cout,
                                                     int M, int N, int Kred, int ldk) {
  constexpr int BM = 128, BN = 128, BK = 64;
  constexpr int MI = 4, NI = 4;   // per-wave 64x64, 2x2 waves
  __shared__ alignas(16) __bf16 Bl[BN * BK];   // 16 KB

  const int tid = threadIdx.x;
  const int wid = tid >> 6;
  const int lane = tid & 63;
  const int l15 = lane & 15, lhi = lane >> 4;
  const int wr = wid >> 1, wc = wid & 1;

  const int m0 = blockIdx.x * BM;
  const int n0 = blockIdx.y * BN;
  const int kbase = blockIdx.z * Kred;

  f32x4 acc[MI][NI] = {};

  // per-lane A row pointers (row fixed per mi across the whole K loop)
  const float* arow[MI];
#pragma unroll
  for (int mi = 0; mi < MI; ++mi)
    arow[mi] = Xf + (size_t)(m0 + wr * 64 + mi * 16 + l15) * ldk + lhi * 8;

  for (int k0 = kbase; k0 < kbase + Kred; k0 += BK) {
    // ---- A fragments: 16 dwordx4 loads straight from global (all in flight) ----
    f32x4 ar[MI][2][2];   // [mi][kk][half] — all indices compile-time (rule #20)
#pragma unroll
    for (int mi = 0; mi < MI; ++mi) {
      const float* rp = arow[mi] + k0;
      ar[mi][0][0] = *(const f32x4*)(rp);
      ar[mi][0][1] = *(const f32x4*)(rp + 4);
      ar[mi][1][0] = *(const f32x4*)(rp + 32);
      ar[mi][1][1] = *(const f32x4*)(rp + 36);
    }
    // ---- B tile via global_load_lds: 4 issues x 4 KB = 16 KB (full tile) ----
#pragma unroll
    for (int it = 0; it < 4; ++it) {
      int o = (it * 256 + tid) * 8;
      int row = o / BK;
      int blk = (o % BK) / 8;
      int col = (blk ^ (row & 7)) * 8;
      gload_lds16(Bmat + (size_t)(n0 + row) * ldk + k0 + col,
                  Bl + (it * 256 + wid * 64) * 8);
    }
    __syncthreads();   // one vmcnt(0) drain covers A-reg loads AND B staging

#pragma unroll
    for (int kk = 0; kk < 2; ++kk) {
      bf16x8 af[MI], bfv[NI];
#pragma unroll
      for (int mi = 0; mi < MI; ++mi) {
#pragma unroll
        for (int j = 0; j < 4; ++j) {
          af[mi][j]     = (__bf16)ar[mi][kk][0][j];
          af[mi][4 + j] = (__bf16)ar[mi][kk][1][j];
        }
      }
#pragma unroll
      for (int ni = 0; ni < NI; ++ni) {
        int row = wc * 64 + ni * 16 + l15;
        int blk = (kk * 4 + lhi) ^ (row & 7);
        bfv[ni] = *(const bf16x8*)((const char*)Bl + row * (BK * 2) + blk * 16);
      }
#pragma unroll
      for (int mi = 0; mi < MI; ++mi)
#pragma unroll
        for (int ni = 0; ni < NI; ++ni)
          acc[mi][ni] = __builtin_amdgcn_mfma_f32_16x16x32_bf16(af[mi], bfv[ni],
                                                                acc[mi][ni], 0, 0, 0);
    }
    __syncthreads();   // Bl reused next tile
  }

  // ---- epilogue: C/D layout col=lane&15, row=(lane>>4)*4+reg ----
  __bf16* cbase = Cout + (size_t)blockIdx.z * M * N;
#pragma unroll
  for (int ni = 0; ni < NI; ++ni) {
    int col = n0 + wc * 64 + ni * 16 + l15;
#pragma unroll
    for (int mi = 0; mi < MI; ++mi) {
#pragma unroll
      for (int r = 0; r < 4; ++r) {
        int row = m0 + wr * 64 + mi * 16 + lhi * 4 + r;
        cbase[(size_t)row * N + col] = (__bf16)acc[mi][ni][r];
      }
    }
  }
}

// ------------- GEMM2 (m97 structure, no swizzle): C = A @ B^T + bias, f32 -------------
template <int BM, int BN, int BK>
__global__ __launch_bounds__(256) void gemm_bt_bias(const __bf16* __restrict__ Amat,
                                                    const __bf16* __restrict__ Bmat,
                                                    const float* __restrict__ bias,
                                                    float* __restrict__ Cout,
                                                    int M, int N, int K) {
  constexpr int WM = BM / 2, WN = BN / 2;
  constexpr int MI = WM / 16, NI = WN / 16;
  __shared__ alignas(16) __bf16 Al[BM * BK];
  __shared__ alignas(16) __bf16 Bl[BN * BK];

  const int tid = threadIdx.x;
  const int wid = tid >> 6;
  const int lane = tid & 63;
  const int l15 = lane & 15, lhi = lane >> 4;
  const int wr = wid >> 1, wc = wid & 1;

  const int m0 = blockIdx.x * BM;
  const int n0 = blockIdx.y * BN;

  f32x4 acc[MI][NI] = {};

  for (int k0 = 0; k0 < K; k0 += BK) {
    constexpr int IA = BM * BK / (256 * 8);
#pragma unroll
    for (int it = 0; it < IA; ++it) {
      int o = (it * 256 + tid) * 8;
      int row = o / BK;
      int blk = (o % BK) / 8;
      int col = (blk ^ (row & 7)) * 8;
      gload_lds16(Amat + (size_t)(m0 + row) * K + k0 + col,
                  Al + (it * 256 + wid * 64) * 8);
    }
    constexpr int IB = BN * BK / (256 * 8);
#pragma unroll
    for (int it = 0; it < IB; ++it) {
      int o = (it * 256 + tid) * 8;
      int row = o / BK;
      int blk = (o % BK) / 8;
      int col = (blk ^ (row & 7)) * 8;
      gload_lds16(Bmat + (size_t)(n0 + row) * K + k0 + col,
                  Bl + (it * 256 + wid * 64) * 8);
    }
    __syncthreads();

#pragma unroll
    for (int kk = 0; kk < BK / 32; ++kk) {
      bf16x8 af[MI], bfv[NI];
#pragma unroll
      for (int mi = 0; mi < MI; ++mi) {
        int row = wr * WM + mi * 16 + l15;
        int blk = (kk * 4 + lhi) ^ (row & 7);
        af[mi] = *(const bf16x8*)((const char*)Al + row * (BK * 2) + blk * 16);
      }
#pragma unroll
      for (int ni = 0; ni < NI; ++ni) {
        int row = wc * WN + ni * 16 + l15;
        int blk = (kk * 4 + lhi) ^ (row & 7);
        bfv[ni] = *(const bf16x8*)((const char*)Bl + row * (BK * 2) + blk * 16);
      }
#pragma unroll
      for (int mi = 0; mi < MI; ++mi)
#pragma unroll
        for (int ni = 0; ni < NI; ++ni)
          acc[mi][ni] = __builtin_amdgcn_mfma_f32_16x16x32_bf16(af[mi], bfv[ni],
                                                                acc[mi][ni], 0, 0, 0);
    }
    __syncthreads();
  }

#pragma unroll
  for (int ni = 0; ni < NI; ++ni) {
    int col = n0 + wc * WN + ni * 16 + l15;
    float bv = bias[col];
#pragma unroll
    for (int mi = 0; mi < MI; ++mi) {
#pragma unroll
      for (int r = 0; r < 4; ++r) {
        int row = m0 + wr * WM + mi * 16 + lhi * 4 + r;
        Cout[(size_t)row * N + col] = acc[mi][ni][r] + bv;
      }
    }
  }
}

extern "C" void kernel_launch(void* const* d_in, const int* in_sizes, int n_in,
                              void* d_out, int out_size, void* d_ws, size_t ws_size,
                              hipStream_t stream) {
  const float* x    = (const float*)d_in[0];
  const float* A    = (const float*)d_in[1];
  const float* B    = (const float*)d_in[2];
  const float* bias = (const float*)d_in[3];
  float* out = (float*)d_out;

  // d_out (128+ MiB) doubles as scratch before GEMM2 overwrites it:
  //   [64, 80 MiB) : tp = split-K partials, 2 slices x 8 MiB (consumed by reduce2)
  __bf16* tp = (__bf16*)((char*)d_out + ((size_t)64 << 20));
  char* ws = (char*)d_ws;
  __bf16* Ab = (__bf16*)ws;                        // [D_OUT][RANK] bf16
  __bf16* Bt = (__bf16*)(ws + ((size_t)4 << 20));  // [RANK][D_IN]  bf16
  __bf16* Tt = (__bf16*)(ws + ((size_t)8 << 20));  // [MROWS][RANK] bf16

  hipLaunchKernelGGL(cvt_f32_bf16, dim3(512), dim3(256), 0, stream,
                     A, Ab, (size_t)D_OUT * RANK);
  hipLaunchKernelGGL(transpose_cvt, dim3(D_IN / 64, RANK / 64), dim3(256), 0, stream,
                     B, Bt, D_IN, RANK);
  // t_partial[z] = bf16(x) @ B[:, z*2048:(z+1)*2048]  (A-direct, split-K=2)
  hipLaunchKernelGGL(gemm1_adirect,
                     dim3(MROWS / 128, RANK / 128, 2), dim3(256), 0, stream,
                     x, Bt, tp, MROWS, RANK, D_IN / 2, D_IN);
  // Tt = bf16(tp[0] + tp[1])
  hipLaunchKernelGGL(reduce2_bf16, dim3(MROWS * RANK / (256 * 8)), dim3(256), 0, stream,
                     tp, tp + (size_t)MROWS * RANK, Tt);
  // out = Tt @ A^T + bias
  hipLaunchKernelGGL((gemm_bt_bias<128, 128, 64>),
                     dim3(MROWS / 128, D_OUT / 128), dim3(256), 0, stream,
                     Tt, Ab, bias, out, MROWS, D_OUT, RANK);
}

// Round 12
// 141.845 us; speedup vs baseline: 1.6224x; 1.6224x over previous
//
#include <hip/hip_runtime.h>

typedef __attribute__((ext_vector_type(8))) __bf16 bf16x8;
typedef __attribute__((ext_vector_type(4))) __bf16 bf16x4;
typedef __attribute__((ext_vector_type(4))) float f32x4;

#define D_OUT 4096
#define D_IN  4096
#define RANK  512
#define MROWS 8192   // BATCH*SEQ

__device__ __forceinline__ void gload_lds16(const void* gsrc, void* ldst) {
  __builtin_amdgcn_global_load_lds(
      (const __attribute__((address_space(1))) void*)gsrc,
      (__attribute__((address_space(3))) void*)ldst, 16, 0, 0);
}

// ---------------- f32 -> bf16 elementwise convert ----------------
__global__ __launch_bounds__(256) void cvt_f32_bf16(const float* __restrict__ in,
                                                    __bf16* __restrict__ out,
                                                    size_t n) {
  size_t i = ((size_t)blockIdx.x * 256 + threadIdx.x) * 4;
  size_t stride = (size_t)gridDim.x * 256 * 4;
  for (; i < n; i += stride) {
    float4 v = *(const float4*)(in + i);
    bf16x4 o = {(__bf16)v.x, (__bf16)v.y, (__bf16)v.z, (__bf16)v.w};
    *(bf16x4*)(out + i) = o;
  }
}

// ------------- f32 [R][C] -> bf16 [C][R] transpose-convert (B) -------------
__global__ __launch_bounds__(256) void transpose_cvt(const float* __restrict__ in,
                                                     __bf16* __restrict__ out,
                                                     int R, int C) {
  __shared__ __bf16 tile[64][72];
  const int r0 = blockIdx.x * 64, c0 = blockIdx.y * 64;
  const int t = threadIdx.x;
  const int tr = t / 16, tc4 = (t % 16) * 4;
#pragma unroll
  for (int i = 0; i < 4; ++i) {
    int r = i * 16 + tr;
    float4 v = *(const float4*)(in + (size_t)(r0 + r) * C + c0 + tc4);
    tile[r][tc4 + 0] = (__bf16)v.x;
    tile[r][tc4 + 1] = (__bf16)v.y;
    tile[r][tc4 + 2] = (__bf16)v.z;
    tile[r][tc4 + 3] = (__bf16)v.w;
  }
  __syncthreads();
#pragma unroll
  for (int i = 0; i < 4; ++i) {
    int c = i * 16 + tr;
    bf16x4 o = {tile[tc4 + 0][c], tile[tc4 + 1][c], tile[tc4 + 2][c], tile[tc4 + 3][c]};
    *(bf16x4*)(out + (size_t)(c0 + c) * R + r0 + tc4) = o;
  }
}

// ---------------- partial-sum reduce + cvt: o = bf16(t0 + t1) ----------------
__global__ __launch_bounds__(256) void reduce2_bf16(const __bf16* __restrict__ t0,
                                                    const __bf16* __restrict__ t1,
                                                    __bf16* __restrict__ o) {
  size_t i = ((size_t)blockIdx.x * 256 + threadIdx.x) * 8;
  bf16x8 a = *(const bf16x8*)(t0 + i);
  bf16x8 b = *(const bf16x8*)(t1 + i);
  bf16x8 r;
#pragma unroll
  for (int j = 0; j < 8; ++j) r[j] = (__bf16)((float)a[j] + (float)b[j]);
  *(bf16x8*)(o + i) = r;
}

// ------- GEMM, 2-phase double-buffered (T3 minimal), NO XCD swizzle -------
// Per K-tile: issue STAGE(t+1 -> buf^1) FIRST, then ds_read+MFMA tile t from
// buf, then one __syncthreads() (its vmcnt drain waits on loads issued a full
// compute-phase earlier -> overlapped). K-split via blockIdx.z.
template <int BM, int BN, int BK, bool OUT_F32, bool BIAS>
__global__ __launch_bounds__(256) void gemm_bt(const __bf16* __restrict__ Amat,
                                               const __bf16* __restrict__ Bmat,
                                               const float* __restrict__ bias,
                                               void* __restrict__ Cout,
                                               int M, int N, int Kred, int ldk) {
  constexpr int WM = BM / 2, WN = BN / 2;
  constexpr int MI = WM / 16, NI = WN / 16;
  __shared__ alignas(16) __bf16 Al[2][BM * BK];
  __shared__ alignas(16) __bf16 Bl[2][BN * BK];

  const int tid = threadIdx.x;
  const int wid = tid >> 6;
  const int lane = tid & 63;
  const int l15 = lane & 15, lhi = lane >> 4;
  const int wr = wid >> 1, wc = wid & 1;

  // plain tile mapping (no XCD swizzle — L3-resident regime, R6 evidence)
  const int m0 = blockIdx.x * BM;
  const int n0 = blockIdx.y * BN;
  const int kbase = blockIdx.z * Kred;
  const int nt = Kred / BK;

  f32x4 acc[MI][NI] = {};

  auto stage = [&](int k0, int b) {
    constexpr int IA = BM * BK / (256 * 8);
#pragma unroll
    for (int it = 0; it < IA; ++it) {
      int o = (it * 256 + tid) * 8;
      int row = o / BK;
      int blk = (o % BK) / 8;
      int col = (blk ^ (row & 7)) * 8;
      gload_lds16(Amat + (size_t)(m0 + row) * ldk + k0 + col,
                  &Al[b][(it * 256 + wid * 64) * 8]);
    }
    constexpr int IB = BN * BK / (256 * 8);
#pragma unroll
    for (int it = 0; it < IB; ++it) {
      int o = (it * 256 + tid) * 8;
      int row = o / BK;
      int blk = (o % BK) / 8;
      int col = (blk ^ (row & 7)) * 8;
      gload_lds16(Bmat + (size_t)(n0 + row) * ldk + k0 + col,
                  &Bl[b][(it * 256 + wid * 64) * 8]);
    }
  };

  stage(kbase, 0);
  __syncthreads();

  for (int t = 0; t < nt; ++t) {
    if (t + 1 < nt) stage(kbase + (t + 1) * BK, (t + 1) & 1);

    const char* Ab_ = (const char*)Al[t & 1];
    const char* Bb_ = (const char*)Bl[t & 1];
#pragma unroll
    for (int kk = 0; kk < BK / 32; ++kk) {
      bf16x8 af[MI], bfv[NI];
#pragma unroll
      for (int mi = 0; mi < MI; ++mi) {
        int row = wr * WM + mi * 16 + l15;
        int blk = (kk * 4 + lhi) ^ (row & 7);
        af[mi] = *(const bf16x8*)(Ab_ + row * (BK * 2) + blk * 16);
      }
#pragma unroll
      for (int ni = 0; ni < NI; ++ni) {
        int row = wc * WN + ni * 16 + l15;
        int blk = (kk * 4 + lhi) ^ (row & 7);
        bfv[ni] = *(const bf16x8*)(Bb_ + row * (BK * 2) + blk * 16);
      }
#pragma unroll
      for (int mi = 0; mi < MI; ++mi)
#pragma unroll
        for (int ni = 0; ni < NI; ++ni)
          acc[mi][ni] = __builtin_amdgcn_mfma_f32_16x16x32_bf16(af[mi], bfv[ni],
                                                                acc[mi][ni], 0, 0, 0);
    }
    __syncthreads();  // drains vmcnt: stage(t+1) was issued BEFORE compute(t)
  }

  // ---- epilogue: C/D layout col=lane&15, row=(lane>>4)*4+reg ----
  char* cbase = (char*)Cout + (size_t)blockIdx.z * M * N * (OUT_F32 ? 4 : 2);
#pragma unroll
  for (int ni = 0; ni < NI; ++ni) {
    int col = n0 + wc * WN + ni * 16 + l15;
    float bv = 0.f;
    if constexpr (BIAS) bv = bias[col];
#pragma unroll
    for (int mi = 0; mi < MI; ++mi) {
#pragma unroll
      for (int r = 0; r < 4; ++r) {
        int row = m0 + wr * WM + mi * 16 + lhi * 4 + r;
        if constexpr (OUT_F32)
          ((float*)cbase)[(size_t)row * N + col] = acc[mi][ni][r] + bv;
        else
          ((__bf16*)cbase)[(size_t)row * N + col] = (__bf16)acc[mi][ni][r];
      }
    }
  }
}

extern "C" void kernel_launch(void* const* d_in, const int* in_sizes, int n_in,
                              void* d_out, int out_size, void* d_ws, size_t ws_size,
                              hipStream_t stream) {
  const float* x    = (const float*)d_in[0];
  const float* A    = (const float*)d_in[1];
  const float* B    = (const float*)d_in[2];
  const float* bias = (const float*)d_in[3];
  float* out = (float*)d_out;

  // d_out (128+ MiB) doubles as scratch before GEMM2 overwrites it:
  //   [0, 64 MiB)  : xb  = bf16(x)            (consumed by GEMM1)
  //   [64, 80 MiB) : tp  = split-K partials   (consumed by reduce2)
  __bf16* xb = (__bf16*)d_out;
  __bf16* tp = (__bf16*)((char*)d_out + ((size_t)64 << 20));
  char* ws = (char*)d_ws;
  __bf16* Ab = (__bf16*)ws;                        // [D_OUT][RANK] bf16
  __bf16* Bt = (__bf16*)(ws + ((size_t)4 << 20));  // [RANK][D_IN]  bf16
  __bf16* Tt = (__bf16*)(ws + ((size_t)8 << 20));  // [MROWS][RANK] bf16

  hipLaunchKernelGGL(cvt_f32_bf16, dim3(2048), dim3(256), 0, stream,
                     x, xb, (size_t)MROWS * D_IN);
  hipLaunchKernelGGL(cvt_f32_bf16, dim3(512), dim3(256), 0, stream,
                     A, Ab, (size_t)D_OUT * RANK);
  hipLaunchKernelGGL(transpose_cvt, dim3(D_IN / 64, RANK / 64), dim3(256), 0, stream,
                     B, Bt, D_IN, RANK);
  // t_partial[z] = bf16(x) @ B[:, z*2048:(z+1)*2048]   (split-K=2, dbuf)
  hipLaunchKernelGGL((gemm_bt<128, 128, 64, false, false>),
                     dim3(MROWS / 128, RANK / 128, 2), dim3(256), 0, stream,
                     xb, Bt, nullptr, tp, MROWS, RANK, D_IN / 2, D_IN);
  // Tt = bf16(tp[0] + tp[1])
  hipLaunchKernelGGL(reduce2_bf16, dim3(MROWS * RANK / (256 * 8)), dim3(256), 0, stream,
                     tp, tp + (size_t)MROWS * RANK, Tt);
  // out = Tt @ A^T + bias   (dbuf, no swizzle)
  hipLaunchKernelGGL((gemm_bt<128, 128, 64, true, true>),
                     dim3(MROWS / 128, D_OUT / 128, 1), dim3(256), 0, stream,
                     Tt, Ab, bias, out, MROWS, D_OUT, RANK, RANK);
}